// Round 3
// baseline (439.680 us; speedup 1.0000x reference)
//
#include <hip/hip_runtime.h>

typedef __attribute__((ext_vector_type(8))) short bf16x8;
typedef __attribute__((ext_vector_type(4))) float f32x4;

#if __has_builtin(__builtin_amdgcn_exp2f)
#define EXP2(x) __builtin_amdgcn_exp2f(x)
#else
#define EXP2(x) exp2f(x)
#endif

__device__ __forceinline__ unsigned short f2bf(float f) {
    union { float f; unsigned int u; } v; v.f = f;
    unsigned int r = v.u + 0x7fffu + ((v.u >> 16) & 1u);
    return (unsigned short)(r >> 16);
}

__device__ __forceinline__ float asf(unsigned int u) {
    union { unsigned int u; float f; } v; v.u = u; return v.f;
}

// sqrt( (1/sqrt(32)) * log2(e) ) — baked into BOTH xqT operands so QK^T
// emerges pre-multiplied by scale*log2e: exp2(score) == softmax numerator.
#define QK_PRESCALE 0.50500983f

// ---------------------------------------------------------------------------
// Kernel 1: grouped 1x1 conv.  x[h][i][n] = sum_j W[g][i][j] p[h][j][n] + b
// Writes xqT [h][n][i] (bf16, i contiguous, PRE-SCALED)  -> QK MFMA operands
//        xv  [h][i][n] (bf16, n contiguous)              -> PV A-op (V=elu(x))
// ---------------------------------------------------------------------------
__global__ __launch_bounds__(256) void conv_kernel(
    const float* __restrict__ points, const float* __restrict__ conv_w,
    const float* __restrict__ conv_b,
    unsigned short* __restrict__ xqT, unsigned short* __restrict__ xv)
{
    __shared__ float w[1024];
    const int h  = blockIdx.x >> 4;   // 16 heads
    const int nc = blockIdx.x & 15;   // 16 n-chunks of 256
    const int g  = h & 7;
    const int tid = threadIdx.x;
    const float* wg = conv_w + g * 1024;
    for (int k = tid; k < 1024; k += 256) w[k] = wg[k];
    __syncthreads();
    const int n = nc * 256 + tid;
    const float* p = points + (size_t)h * 32 * 4096 + n;
    float pv[32];
#pragma unroll
    for (int j = 0; j < 32; ++j) pv[j] = p[(size_t)j * 4096];
    float out[32];
#pragma unroll
    for (int i = 0; i < 32; ++i) {
        float acc = conv_b[g * 32 + i];
#pragma unroll
        for (int j = 0; j < 32; ++j) acc += w[i * 32 + j] * pv[j];
        out[i] = acc;
    }
    unsigned short tq[32];
#pragma unroll
    for (int i = 0; i < 32; ++i) tq[i] = f2bf(out[i] * QK_PRESCALE);
    bf16x8* dst = (bf16x8*)(xqT + ((size_t)h * 4096 + n) * 32);
#pragma unroll
    for (int t = 0; t < 4; ++t) dst[t] = ((bf16x8*)tq)[t];
#pragma unroll
    for (int i = 0; i < 32; ++i) {
        float x = out[i];
        float e = x > 0.f ? x : (__expf(x) - 1.f);   // elu
        xv[((size_t)h * 32 + i) * 4096 + n] = f2bf(e);
    }
}

// ---------------------------------------------------------------------------
// Kernel 2: flash attention, LDS-staged (R1 structure) + VALU diet.
//   - 128 queries/block: 4 waves x 2 Q-fragments (mA, mB = +16)
//   - 128-key staging chunks (one barrier pair per 128 keys)
//   - compute in 64-key sub-tiles; per-wave P transpose buffer (no barrier:
//     per-wave DS ops are in-order, compiler inserts lgkmcnt)
//   - no-max softmax (|log2 scores| << 126, fp32 exp2 safe)
//   - epilogue: channel shuffle + residual + fused GroupNorm partial stats
//     (gn group == i), atomicAdd into stats[64][2]
// ---------------------------------------------------------------------------
#define KSTR 40    // 32 + 8 pad shorts
#define VSTR 136   // 128 + 8 pad shorts
#define PSTR 72    // 64 + 8 pad shorts

__device__ __forceinline__ uint2 exp_pack(f32x4 sc, float& lsum) {
    union { float f; unsigned int u; } e0, e1, e2, e3;
    e0.f = EXP2(sc[0]); e1.f = EXP2(sc[1]); e2.f = EXP2(sc[2]); e3.f = EXP2(sc[3]);
    unsigned int t0 = e0.u & 0xffff0000u, t1 = e1.u & 0xffff0000u;
    unsigned int t2 = e2.u & 0xffff0000u, t3 = e3.u & 0xffff0000u;
    // denominator over the TRUNCATED values -> weights sum to exactly 1
    lsum += (asf(t0) + asf(t1)) + (asf(t2) + asf(t3));
    uint2 pk; pk.x = (t0 >> 16) | t1; pk.y = (t2 >> 16) | t3;
    return pk;
}

__global__ __launch_bounds__(256) void attn_kernel(
    const unsigned short* __restrict__ xqT,
    const unsigned short* __restrict__ xv,
    const float* __restrict__ points,
    float* __restrict__ z, float* __restrict__ stats)
{
    __shared__ unsigned short Kt[128 * KSTR];     // [n][i]     10240 B
    __shared__ unsigned short Vt[32 * VSTR];      // [i][n]      8704 B
    __shared__ unsigned short Pl[4][32 * PSTR];   // per-wave   18432 B

    const int h  = blockIdx.y;
    const int b = h >> 3, g = h & 7;
    const int tid = threadIdx.x;
    const int wv = tid >> 6, lane = tid & 63;
    const int quad = lane >> 4, l15 = lane & 15;

    const int mbase = blockIdx.x * 128 + wv * 32;
    const int mA = mbase + l15, mB = mbase + 16 + l15;

    const unsigned short* kbase = xqT + (size_t)h * 4096 * 32;
    const unsigned short* vbase = xv  + (size_t)h * 32 * 4096;

    // Q fragments (B-operand): col=l15, k=quad*8+j
    const bf16x8 qfragA = *(const bf16x8*)(kbase + (size_t)mA * 32 + quad * 8);
    const bf16x8 qfragB = *(const bf16x8*)(kbase + (size_t)mB * 32 + quad * 8);

    f32x4 accA0 = {0,0,0,0}, accA1 = {0,0,0,0};
    f32x4 accB0 = {0,0,0,0}, accB1 = {0,0,0,0};
    float lsumA = 0.f, lsumB = 0.f;

    const int kr = tid >> 2, kc = (tid & 3) * 8;   // K staging [n][i]
    const int vi = tid >> 3, vn = (tid & 7) * 8;   // V staging [i][n]
    unsigned short* pw = &Pl[wv][0];

    for (int n0 = 0; n0 < 4096; n0 += 128) {
        __syncthreads();
        *(bf16x8*)(Kt + kr * KSTR + kc) =
            *(const bf16x8*)(kbase + (size_t)(n0 + kr) * 32 + kc);
        *(bf16x8*)(Kt + (kr + 64) * KSTR + kc) =
            *(const bf16x8*)(kbase + (size_t)(n0 + 64 + kr) * 32 + kc);
        *(bf16x8*)(Vt + vi * VSTR + vn) =
            *(const bf16x8*)(vbase + (size_t)vi * 4096 + n0 + vn);
        *(bf16x8*)(Vt + vi * VSTR + 64 + vn) =
            *(const bf16x8*)(vbase + (size_t)vi * 4096 + n0 + 64 + vn);
        __syncthreads();

#pragma unroll
        for (int sub = 0; sub < 2; ++sub) {
#pragma unroll
            for (int s = 0; s < 4; ++s) {
                // A-operand K^T: A[r=n][k=i], lane r=l15
                const bf16x8 kf = *(const bf16x8*)(
                    Kt + (sub * 64 + s * 16 + l15) * KSTR + quad * 8);
                f32x4 scA = __builtin_amdgcn_mfma_f32_16x16x32_bf16(
                    kf, qfragA, (f32x4){0,0,0,0}, 0, 0, 0);
                f32x4 scB = __builtin_amdgcn_mfma_f32_16x16x32_bf16(
                    kf, qfragB, (f32x4){0,0,0,0}, 0, 0, 0);
                // C/D: col=l15 (query), row n = s*16 + quad*4 + r
                uint2 pkA = exp_pack(scA, lsumA);
                uint2 pkB = exp_pack(scB, lsumB);
                *(uint2*)(pw + l15 * PSTR + s * 16 + quad * 4) = pkA;
                *(uint2*)(pw + (16 + l15) * PSTR + s * 16 + quad * 4) = pkB;
            }
#pragma unroll
            for (int ng = 0; ng < 2; ++ng) {
                // B-operand P: col=l15, k = ng*32+quad*8+j
                bf16x8 pfA = *(const bf16x8*)(pw + l15 * PSTR + ng * 32 + quad * 8);
                bf16x8 pfB = *(const bf16x8*)(pw + (16 + l15) * PSTR + ng * 32 + quad * 8);
                const int col = sub * 64 + ng * 32 + quad * 8;
                // A-operand V: A[r=i][k=n]
                bf16x8 v0 = *(const bf16x8*)(Vt + l15 * VSTR + col);
                bf16x8 v1 = *(const bf16x8*)(Vt + (16 + l15) * VSTR + col);
                accA0 = __builtin_amdgcn_mfma_f32_16x16x32_bf16(v0, pfA, accA0, 0, 0, 0);
                accA1 = __builtin_amdgcn_mfma_f32_16x16x32_bf16(v1, pfA, accA1, 0, 0, 0);
                accB0 = __builtin_amdgcn_mfma_f32_16x16x32_bf16(v0, pfB, accB0, 0, 0, 0);
                accB1 = __builtin_amdgcn_mfma_f32_16x16x32_bf16(v1, pfB, accB1, 0, 0, 0);
            }
        }
    }

    // denominators: sum partials over the 4 quads sharing each query column
    lsumA += __shfl_xor(lsumA, 16, 64);
    lsumA += __shfl_xor(lsumA, 32, 64);
    lsumB += __shfl_xor(lsumB, 16, 64);
    lsumB += __shfl_xor(lsumB, 32, 64);
    const float invA = 1.f / lsumA, invB = 1.f / lsumB;

    const float* pb = points + (size_t)b * 256 * 4096;
    float* zb = z + (size_t)b * 256 * 4096;
    float* sb = stats + (size_t)b * 64;

#pragma unroll
    for (int half = 0; half < 2; ++half) {
        f32x4 aA = half ? accA1 : accA0;
        f32x4 aB = half ? accB1 : accB0;
#pragma unroll
        for (int r = 0; r < 4; ++r) {
            const int i = half * 16 + quad * 4 + r;        // C/D row; == gn group
            const size_t off = (size_t)(i * 8 + g) * 4096; // channel shuffle
            float zA = aA[r] * invA + pb[off + mA];
            float zB = aB[r] * invB + pb[off + mB];
            zb[off + mA] = zA;
            zb[off + mB] = zB;
            // fused GroupNorm partial stats: reduce over the 16 l15 lanes
            float s  = zA + zB;
            float ss = zA * zA + zB * zB;
            s  += __shfl_xor(s, 1, 64);  ss += __shfl_xor(ss, 1, 64);
            s  += __shfl_xor(s, 2, 64);  ss += __shfl_xor(ss, 2, 64);
            s  += __shfl_xor(s, 4, 64);  ss += __shfl_xor(ss, 4, 64);
            s  += __shfl_xor(s, 8, 64);  ss += __shfl_xor(ss, 8, 64);
            if (l15 == 0) {
                atomicAdd(&sb[i * 2], s);
                atomicAdd(&sb[i * 2 + 1], ss);
            }
        }
    }
}

// ---------------------------------------------------------------------------
// Kernel 3: GroupNorm apply, in place on d_out, from fused atomic sums.
// ---------------------------------------------------------------------------
__global__ __launch_bounds__(256) void gn_apply(float* __restrict__ z,
                                                const float* __restrict__ stats,
                                                const float* __restrict__ gw,
                                                const float* __restrict__ gb)
{
    const int idx = blockIdx.x * 256 + threadIdx.x;  // float4 index
    float4* p = (float4*)z;
    float4 v = p[idx];
    const int chg = idx >> 10;       // global channel b*256+ch
    const int blk = chg >> 3;        // stats slot = b*32 + ch/8
    const int ch  = chg & 255;
    const float s = stats[blk * 2], ss = stats[blk * 2 + 1];
    const float mean = s * (1.f / 32768.f);
    const float var  = ss * (1.f / 32768.f) - mean * mean;
    const float rstd = rsqrtf(var + 1e-5f);
    const float w  = gw[ch] * rstd;
    const float bb = gb[ch] - mean * w;
    v.x = v.x * w + bb; v.y = v.y * w + bb;
    v.z = v.z * w + bb; v.w = v.w * w + bb;
    p[idx] = v;
}

extern "C" void kernel_launch(void* const* d_in, const int* in_sizes, int n_in,
                              void* d_out, int out_size, void* d_ws, size_t ws_size,
                              hipStream_t stream)
{
    const float* points = (const float*)d_in[0];
    const float* conv_w = (const float*)d_in[1];
    const float* conv_b = (const float*)d_in[2];
    const float* gn_w   = (const float*)d_in[3];
    const float* gn_b   = (const float*)d_in[4];
    float* out = (float*)d_out;
    char* ws = (char*)d_ws;
    unsigned short* xqT = (unsigned short*)ws;                             // 4 MB
    unsigned short* xv  = (unsigned short*)(ws + (size_t)4 * 1024 * 1024); // 4 MB
    float* stats = (float*)(ws + (size_t)8 * 1024 * 1024);                 // 512 B

    hipMemsetAsync(stats, 0, 64 * 2 * sizeof(float), stream);
    conv_kernel<<<256, 256, 0, stream>>>(points, conv_w, conv_b, xqT, xv);
    attn_kernel<<<dim3(32, 16), 256, 0, stream>>>(xqT, xv, points, out, stats);
    gn_apply<<<2048, 256, 0, stream>>>(out, stats, gn_w, gn_b);
}